// Round 5
// baseline (337.985 us; speedup 1.0000x reference)
//
#include <hip/hip_runtime.h>

// TopK_36653250904599: x [16,256,128,128] f32 -> l2-normalize over HW=16384,
// top-16 values [B,C,16] + (h,w) coords [B,C,16,2] (coords stored as floats).
//
// R11 = R10 resubmitted verbatim (R10 bench died on a container/broker
// failure, not a kernel failure; no counters arrived, theory untested).
//
// R10: one WAVE (64 threads) per row, 4096 single-wave blocks, all
// co-resident (19 blocks/CU LDS-capped, 16 needed). Removes ALL barrier
// coupling: no s_part exchange, tails of independent waves overlap other
// waves' streaming. This attacks the prior session's "barrier-coupled block
// tails throttle streaming to ~2.4 TB/s" mechanism. R9 post-mortem: per-wave
// load pipelining was exactly neutral (compiler already hoists independent
// loads), so per-wave MLP is not the constraint; decomposition is pinned to
// 331 = 161 (one 1-GiB harness poison fill) + kernel + reset overhead.
//
// Bitwise-identical numerics: lane l emulates original 256-thread block's
// threads {w*64+l, w=0..3}: same per-thread fma chains over same elements,
// same 64-lane shfl tree pairing per (quarter,w), lane0 combines in original
// wave order ((w0+w1)+w2)+w3 then quarter order ((q0+q1)+q2)+q3 (leading
// 0+T0 is exact, T>=+0). Scale broadcast from lane0 = same bits. Candidate
// set/packing/tiebreak/fallback unchanged; list ORDER irrelevant (unique).

#define KSEL 16
#define HW   16384
#define WDIM 128
#define CAP  1024
#define T0   2.5f
#define NROWS 4096
#define VALS_TOTAL (NROWS * KSEL)   // 65536 value floats, then coords

typedef float floatx4 __attribute__((ext_vector_type(4)));

__global__ __launch_bounds__(64) void k_fused(const float* __restrict__ x,
                                              float* __restrict__ out) {
    const int row = blockIdx.x;
    const int l   = threadIdx.x;        // lane 0..63 (one wave per block)

    __shared__ unsigned long long s_cand[CAP];
    __shared__ unsigned s_cnt;

    if (l == 0) s_cnt = 0;
    __syncthreads();

    const floatx4* p = (const floatx4*)(x + (size_t)row * HW);

    float q[4] = {0.0f, 0.0f, 0.0f, 0.0f};   // per-quarter tree sums (lane 0)

    // process one (quarter c, pseudo-wave w) unit from a 4-float4 reg buffer;
    // identical to original thread t = w*64+l working quarter c.
    auto process = [&](const floatx4* buf, int c, int w) {
        float s = 0.0f;
        #pragma unroll
        for (int k = 0; k < 4; ++k) {
            s = fmaf(buf[k].x, buf[k].x, s);
            s = fmaf(buf[k].y, buf[k].y, s);
            s = fmaf(buf[k].z, buf[k].z, s);
            s = fmaf(buf[k].w, buf[k].w, s);
        }

        unsigned msk = 0;
        #pragma unroll
        for (int k = 0; k < 4; ++k) {
            msk |= (buf[k].x > T0) ? (1u << (4 * k + 0)) : 0u;
            msk |= (buf[k].y > T0) ? (1u << (4 * k + 1)) : 0u;
            msk |= (buf[k].z > T0) ? (1u << (4 * k + 2)) : 0u;
            msk |= (buf[k].w > T0) ? (1u << (4 * k + 3)) : 0u;
        }
        if (msk) {
            unsigned base = atomicAdd(&s_cnt, (unsigned)__popc(msk));
            #pragma unroll
            for (int k = 0; k < 4; ++k) {
                #pragma unroll
                for (int cc = 0; cc < 4; ++cc) {
                    float v = (cc == 0) ? buf[k].x : (cc == 1) ? buf[k].y
                            : (cc == 2) ? buf[k].z : buf[k].w;
                    if (v > T0) {
                        if (base < CAP) {
                            unsigned u  = __float_as_uint(v);
                            unsigned mm = u ^ (((unsigned)((int)u >> 31)) | 0x80000000u);
                            int idx = c * 4096 + (k * 256 + w * 64 + l) * 4 + cc;
                            s_cand[base] = ((unsigned long long)mm << 32) |
                                           (unsigned)(16383 - idx);
                        }
                        base++;
                    }
                }
            }
        }

        // 64-lane tree, identical pairing to the original per-wave reduce
        #pragma unroll
        for (int off = 32; off > 0; off >>= 1)
            s += __shfl_down(s, off, 64);
        if (l == 0) q[c] += s;          // w ascending: ((w0+w1)+w2)+w3 order
    };

    // ---- streaming: 16 units (c = u>>2, w = u&3), 2-deep register pipeline
    floatx4 bufA[4], bufB[4];
    #pragma unroll
    for (int k = 0; k < 4; ++k)
        bufA[k] = __builtin_nontemporal_load(&p[k * 256 + l]);   // unit 0
    #pragma unroll
    for (int u = 0; u < 16; ++u) {
        const int c = u >> 2, w = u & 3;
        if (u < 15) {
            const int cn = (u + 1) >> 2, wn = (u + 1) & 3;
            floatx4* nxt = (u & 1) ? bufA : bufB;
            #pragma unroll
            for (int k = 0; k < 4; ++k)
                nxt[k] = __builtin_nontemporal_load(
                    &p[cn * 1024 + k * 256 + wn * 64 + l]);
            process((u & 1) ? bufB : bufA, c, w);
        } else {
            process((u & 1) ? bufB : bufA, c, w);
        }
    }

    // total/scale in lane 0 (same add order as before), broadcast same bits
    float total = ((q[0] + q[1]) + q[2]) + q[3];
    float scale = 1.0f / sqrtf(fmaxf(total, 1e-12f));
    scale = __shfl(scale, 0, 64);

    __syncthreads();    // single wave: drains LDS ops; pushes + s_cnt visible
    unsigned cnt = s_cnt;

    if (cnt < KSEL || cnt > CAP) {
        // slow path (never for N(0,1)): bisect raw threshold, re-reading row
        const float* xr = x + (size_t)row * HW;
        float T = T0, lo = -3.0e38f, hi = 3.0e38f;
        for (int it = 0; it < 32; ++it) {
            __syncthreads();
            if (l == 0) s_cnt = 0;
            __syncthreads();
            for (int i = l; i < HW; i += 64) {
                float v = xr[i];
                if (v > T) {
                    unsigned slot = atomicAdd(&s_cnt, 1u);
                    if (slot < CAP) {
                        unsigned u  = __float_as_uint(v);
                        unsigned mm = u ^ (((unsigned)((int)u >> 31)) | 0x80000000u);
                        s_cand[slot] = ((unsigned long long)mm << 32) |
                                       (unsigned)(16383 - i);
                    }
                }
            }
            __syncthreads();
            cnt = s_cnt;
            if (cnt >= KSEL && cnt <= CAP) break;
            if (cnt < KSEL) { hi = T; T = (lo < -1.0e38f) ? T - 1.0f : 0.5f * (lo + T); }
            else            { lo = T; T = (hi >  1.0e38f) ? T + 1.0f : 0.5f * (T + hi); }
        }
        if (cnt > CAP) cnt = CAP;
    }

    // repack with normalized fp32-rounded value (rounding ties -> idx-asc
    // tiebreak in low bits matches jax.lax.top_k)
    for (unsigned i = l; i < cnt; i += 64) {
        unsigned long long pk = s_cand[i];
        unsigned m = (unsigned)(pk >> 32);
        unsigned u = (m & 0x80000000u) ? (m ^ 0x80000000u) : ~m;
        float vn = __uint_as_float(u) * scale;
        unsigned u2 = __float_as_uint(vn);
        unsigned m2 = u2 ^ (((unsigned)((int)u2 >> 31)) | 0x80000000u);
        s_cand[i] = ((unsigned long long)m2 << 32) | (pk & 0xFFFFFFFFull);
    }
    __syncthreads();

    // all-pairs rank (ranks unique via idx tiebreak) + write
    for (unsigned i = l; i < cnt; i += 64) {
        unsigned long long pk = s_cand[i];
        int rank = 0;
        for (unsigned j = 0; j < cnt; ++j) rank += (s_cand[j] > pk) ? 1 : 0;
        if (rank < KSEL) {
            unsigned m = (unsigned)(pk >> 32);
            unsigned u = (m & 0x80000000u) ? (m ^ 0x80000000u) : ~m;
            float vn = __uint_as_float(u);
            int idx = 16383 - (int)(unsigned)(pk & 0xFFFFFFFFull);
            out[row * KSEL + rank] = vn;
            float* coor = out + VALS_TOTAL + ((size_t)row * KSEL + rank) * 2;
            coor[0] = (float)(idx >> 7);          // h
            coor[1] = (float)(idx & (WDIM - 1));  // w
        }
    }
}

extern "C" void kernel_launch(void* const* d_in, const int* in_sizes, int n_in,
                              void* d_out, int out_size, void* d_ws, size_t ws_size,
                              hipStream_t stream) {
    const float* x = (const float*)d_in[0];
    float* out = (float*)d_out;
    (void)d_ws; (void)ws_size;  // workspace unused: single self-contained launch
    k_fused<<<NROWS, 64, 0, stream>>>(x, out);
}

// Round 6
// 330.111 us; speedup vs baseline: 1.0239x; 1.0239x over previous
//
#include <hip/hip_runtime.h>

// TopK_36653250904599: x [16,256,128,128] f32 -> l2-normalize over HW=16384,
// top-16 values [B,C,16] + (h,w) coords [B,C,16,2] (coords stored as floats).
//
// R12 = R7 reverted verbatim (best measured: 331.2 us; reproduced 331.3 in
// R9). Session findings:
//  - R8  (16 waves/CU, cached loads): +26 us -> occupancy cliff is real.
//  - R9  (2-deep load pipeline):      neutral -> compiler already hoists.
//  - R11 (1 wave/row, 19 waves/CU):   +7 us  -> streaming is TLP-hidden;
//         barrier-coupled tails were NOT the throttle (Model C refuted).
// Decomposition: 331 = 161 (one 1-GiB harness poison fill @6.6 TB/s,
// untouchable) + ~50-55 (kernel, vs 42.6-us floor = 268.4 MB @ 6.3 TB/s)
// + ~115 (harness reset dispatches). Kernel ~85% of its read floor at
// 32 waves/CU; this 256-thread shape is the occupancy optimum (32>19>16).
//
// Numerics bitwise-identical to the verified R6/R7 lineage: per-quarter fma
// chain order, 64-lane shfl tree, wave-then-quarter add order, candidate
// packing, idx-asc tiebreak, bisection fallback (never fires for N(0,1)).

#define KSEL 16
#define HW   16384
#define WDIM 128
#define CAP  1024
#define T0   2.5f
#define NROWS 4096
#define VALS_TOTAL (NROWS * KSEL)   // 65536 value floats, then coords

typedef float floatx4 __attribute__((ext_vector_type(4)));

__global__ __launch_bounds__(256) void k_fused(const float* __restrict__ x,
                                               float* __restrict__ out) {
    const int row  = blockIdx.x;
    const int t    = threadIdx.x;
    const int lane = t & 63;
    const int wv   = t >> 6;

    __shared__ unsigned long long s_cand[CAP];
    __shared__ float s_part[4][4];      // [quarter][wave]
    __shared__ unsigned s_cnt;

    if (t == 0) s_cnt = 0;
    __syncthreads();

    const floatx4* p = (const floatx4*)(x + (size_t)row * HW);

    // ---- streaming phase: no barriers inside the loop ----
    float sqsum[4];
    #pragma unroll
    for (int c = 0; c < 4; ++c) {
        floatx4 buf[4];
        #pragma unroll
        for (int k = 0; k < 4; ++k)
            buf[k] = __builtin_nontemporal_load(&p[c * 1024 + k * 256 + t]);

        float s = 0.0f;
        #pragma unroll
        for (int k = 0; k < 4; ++k) {
            s = fmaf(buf[k].x, buf[k].x, s);
            s = fmaf(buf[k].y, buf[k].y, s);
            s = fmaf(buf[k].z, buf[k].z, s);
            s = fmaf(buf[k].w, buf[k].w, s);
        }
        sqsum[c] = s;

        // branchless 16-bit candidate mask, one reservation atomic per thread
        unsigned msk = 0;
        #pragma unroll
        for (int k = 0; k < 4; ++k) {
            msk |= (buf[k].x > T0) ? (1u << (4 * k + 0)) : 0u;
            msk |= (buf[k].y > T0) ? (1u << (4 * k + 1)) : 0u;
            msk |= (buf[k].z > T0) ? (1u << (4 * k + 2)) : 0u;
            msk |= (buf[k].w > T0) ? (1u << (4 * k + 3)) : 0u;
        }
        if (msk) {
            unsigned base = atomicAdd(&s_cnt, (unsigned)__popc(msk));
            #pragma unroll
            for (int k = 0; k < 4; ++k) {
                #pragma unroll
                for (int cc = 0; cc < 4; ++cc) {
                    float v = (cc == 0) ? buf[k].x : (cc == 1) ? buf[k].y
                            : (cc == 2) ? buf[k].z : buf[k].w;
                    if (v > T0) {
                        if (base < CAP) {
                            unsigned u  = __float_as_uint(v);
                            unsigned mm = u ^ (((unsigned)((int)u >> 31)) | 0x80000000u);
                            int idx = c * 4096 + (k * 256 + t) * 4 + cc; // in-row idx
                            s_cand[base] = ((unsigned long long)mm << 32) |
                                           (unsigned)(16383 - idx);
                        }
                        base++;
                    }
                }
            }
        }
    }

    // ---- per-quarter wave-tree reduction (same order as R6) ----
    #pragma unroll
    for (int c = 0; c < 4; ++c) {
        float s = sqsum[c];
        #pragma unroll
        for (int off = 32; off > 0; off >>= 1)
            s += __shfl_down(s, off, 64);
        if (lane == 0) s_part[c][wv] = s;
    }
    __syncthreads();    // s_part + all candidate pushes visible

    // same add order as R6: qsum[c] = ((w0+w1)+w2)+w3; total = ((q0+q1)+q2)+q3
    const float q0 = s_part[0][0] + s_part[0][1] + s_part[0][2] + s_part[0][3];
    const float q1 = s_part[1][0] + s_part[1][1] + s_part[1][2] + s_part[1][3];
    const float q2 = s_part[2][0] + s_part[2][1] + s_part[2][2] + s_part[2][3];
    const float q3 = s_part[3][0] + s_part[3][1] + s_part[3][2] + s_part[3][3];
    const float scale = 1.0f / sqrtf(fmaxf(q0 + q1 + q2 + q3, 1e-12f));

    unsigned cnt = s_cnt;   // uniform: read after barrier, no writes since

    if (cnt < KSEL || cnt > CAP) {
        // slow path (never for N(0,1)): bisect raw threshold, re-reading row
        const float* xr = x + (size_t)row * HW;
        float T = T0, lo = -3.0e38f, hi = 3.0e38f;
        for (int it = 0; it < 32; ++it) {
            __syncthreads();
            if (t == 0) s_cnt = 0;
            __syncthreads();
            for (int i = t; i < HW; i += 256) {
                float v = xr[i];
                if (v > T) {
                    unsigned slot = atomicAdd(&s_cnt, 1u);
                    if (slot < CAP) {
                        unsigned u  = __float_as_uint(v);
                        unsigned mm = u ^ (((unsigned)((int)u >> 31)) | 0x80000000u);
                        s_cand[slot] = ((unsigned long long)mm << 32) |
                                       (unsigned)(16383 - i);
                    }
                }
            }
            __syncthreads();
            cnt = s_cnt;
            if (cnt >= KSEL && cnt <= CAP) break;
            if (cnt < KSEL) { hi = T; T = (lo < -1.0e38f) ? T - 1.0f : 0.5f * (lo + T); }
            else            { lo = T; T = (hi >  1.0e38f) ? T + 1.0f : 0.5f * (T + hi); }
        }
        if (cnt > CAP) cnt = CAP;
    }

    // repack with normalized fp32-rounded value (rounding ties -> idx-asc
    // tiebreak in low bits matches jax.lax.top_k)
    for (unsigned i = t; i < cnt; i += 256) {
        unsigned long long pk = s_cand[i];
        unsigned m = (unsigned)(pk >> 32);
        unsigned u = (m & 0x80000000u) ? (m ^ 0x80000000u) : ~m;
        float vn = __uint_as_float(u) * scale;
        unsigned u2 = __float_as_uint(vn);
        unsigned m2 = u2 ^ (((unsigned)((int)u2 >> 31)) | 0x80000000u);
        s_cand[i] = ((unsigned long long)m2 << 32) | (pk & 0xFFFFFFFFull);
    }
    __syncthreads();

    // all-pairs rank (ranks unique via idx tiebreak) + write
    for (unsigned i = t; i < cnt; i += 256) {
        unsigned long long pk = s_cand[i];
        int rank = 0;
        for (unsigned j = 0; j < cnt; ++j) rank += (s_cand[j] > pk) ? 1 : 0;
        if (rank < KSEL) {
            unsigned m = (unsigned)(pk >> 32);
            unsigned u = (m & 0x80000000u) ? (m ^ 0x80000000u) : ~m;
            float vn = __uint_as_float(u);
            int idx = 16383 - (int)(unsigned)(pk & 0xFFFFFFFFull);
            out[row * KSEL + rank] = vn;
            float* coor = out + VALS_TOTAL + ((size_t)row * KSEL + rank) * 2;
            coor[0] = (float)(idx >> 7);          // h
            coor[1] = (float)(idx & (WDIM - 1));  // w
        }
    }
}

extern "C" void kernel_launch(void* const* d_in, const int* in_sizes, int n_in,
                              void* d_out, int out_size, void* d_ws, size_t ws_size,
                              hipStream_t stream) {
    const float* x = (const float*)d_in[0];
    float* out = (float*)d_out;
    (void)d_ws; (void)ws_size;  // workspace unused: single self-contained launch
    k_fused<<<NROWS, 256, 0, stream>>>(x, out);
}